// Round 11
// baseline (1060.024 us; speedup 1.0000x reference)
//
#include <hip/hip_runtime.h>
#include <cstdint>

#define NB   4      // batches
#define NPT  8192   // points
#define NC   256    // feature channels
#define NS   1024   // FPS samples
#define NK   64     // neighbors per ball
#define FPT  32     // points per thread in FPS (8192 / 256 threads)

typedef float v2f __attribute__((ext_vector_type(2)));

// ---------------------------------------------------------------------------
// DPP max step (f32, old=0 fill — safe: all reduced values >= 0).
// ---------------------------------------------------------------------------
template <int CTRL, int RMASK>
__device__ __forceinline__ float dpp_max_step(float x) {
    const int t = __builtin_amdgcn_update_dpp(
        0, __float_as_int(x), CTRL, RMASK, 0xf, false);
    return fmaxf(x, __int_as_float(t));
}
__device__ __forceinline__ float wave_max_f32(float x) {
    x = dpp_max_step<0x111, 0xf>(x);  // row_shr:1
    x = dpp_max_step<0x112, 0xf>(x);  // row_shr:2
    x = dpp_max_step<0x114, 0xf>(x);  // row_shr:4
    x = dpp_max_step<0x118, 0xf>(x);  // row_shr:8
    x = dpp_max_step<0x142, 0xa>(x);  // row_bcast:15 -> rows 1,3
    x = dpp_max_step<0x143, 0xc>(x);  // row_bcast:31 -> rows 2,3
    return x;                          // lane 63 holds wave max
}

// ---------------------------------------------------------------------------
// Kernel 1: farthest point sampling. One 256-thread block (4 waves = 1 per
// SIMD) per batch. Compute/reduce = round 7 VERBATIM (best measured; r9/r10
// both showed the instruction count is NOT reducible at source level —
// identical VALUBusy*dur proxy). This round removes the sync tail instead:
//
// BARRIER-FREE, ATOMIC-FREE handshake (spin-poll on step-tagged slots):
//  - slot layout (u64): [ val f32 bits (63:32) | tag = s&0xFF (31:24) |
//                         0xFFFFFF - idx (23:0) ]  (idx < 8192 fits 24b,
//    no carry into tag). Within one step all tags equal, so u64 max ==
//    max value, ties -> smallest index (VERIFIED semantics from r5/r7).
//  - wave w's delegate ds_write_b64's its candidate to slots[(s+1)&1][w]
//    at the bottom of step s (publish for step s+1; prefill covers s=0 with
//    a +inf key for index 0 = deterministic start).
//  - loop top: all lanes poll the 4 slots of parity s&1 (uniform b64 reads,
//    parallel) until all tags == s&0xFF, then 3-compare u64 tournament in
//    registers. No s_barrier, no atomic, no separate post-barrier key read.
//  - race-freedom: wave A publishes for s+1 only after passing poll(s);
//    poll(s) passes only after ALL waves published s, which happens only
//    after they passed poll(s-1) and consumed the s-1 entries — so the
//    buffer being overwritten (parity of s+1 == parity of s-1) is dead.
//    Tags disambiguate any stale observation mid-poll.
//  - termination: every wave publishes unconditionally before polling ->
//    all polls eventually succeed. LDS is CU-local and coherent across the
//    block's waves; b64 DS ops are single-instruction.
// First-occurrence argmax within a wave (VERIFIED r1-r10): x-half =
// tid*32+0..15, y-half = tid*32+16..31; strict-> per half keeps earliest
// index; combine prefers x; lowest achieving lane via ballot+ffs.
// NOTE: non-FMA left-to-right distance arithmetic (contract off) is VERIFIED
// bit-exact vs the reference (rounds 1-10). Do not "optimize" into FMA.
// ---------------------------------------------------------------------------
__global__ __launch_bounds__(256, 1) void fps_kernel(
    const float* __restrict__ xyz, float* __restrict__ sample_xyz)
{
    const int b    = blockIdx.x;
    const int tid  = threadIdx.x;
    const int lane = tid & 63;
    const int wv   = tid >> 6;

    __shared__ float Xs[NPT], Ys[NPT], Zs[NPT];        // 96 KB SoA copy
    __shared__ float Samp[NS * 3];                     // 12 KB result buffer
    __shared__ unsigned long long slots[2][4];         // tagged candidate keys

    const float* base = xyz + (size_t)b * NPT * 3;

    v2f px[16], py[16], pz[16], md[16];
#pragma unroll
    for (int j = 0; j < 16; ++j) {
        const int pa = tid * FPT + j;         // x-half point
        const int pb = tid * FPT + 16 + j;    // y-half point
        const float ax = base[pa * 3 + 0], ay = base[pa * 3 + 1], az = base[pa * 3 + 2];
        const float bx = base[pb * 3 + 0], by = base[pb * 3 + 1], bz = base[pb * 3 + 2];
        px[j] = (v2f){ax, bx};
        py[j] = (v2f){ay, by};
        pz[j] = (v2f){az, bz};
        md[j] = (v2f){__builtin_inff(), __builtin_inff()};
        Xs[pa] = ax; Ys[pa] = ay; Zs[pa] = az;
        Xs[pb] = bx; Ys[pb] = by; Zs[pb] = bz;
    }
    if (tid == 0) {
        // step-0 prefill: +inf value, idx 0, tag 0 -> point 0 wins step 0
        slots[0][0] = ((unsigned long long)0x7F800000u << 32) | 0x00FFFFFFull;
    }
    if (tid < 3) slots[0][tid + 1] = 0ull;   // value 0, tag 0, never wins
    __syncthreads();   // staging + prefill visible to all waves

    for (int s = 0; s < NS; ++s) {
        const int par = s & 1;
        const unsigned tag = (unsigned)s & 0xFFu;

        // ---- spin-poll the 4 tagged slots (uniform b64 broadcast reads) ----
        const volatile unsigned long long* sp = slots[par];
        unsigned long long k0, k1, k2, k3;
        for (;;) {
            k0 = sp[0]; k1 = sp[1]; k2 = sp[2]; k3 = sp[3];
            const unsigned m = (((unsigned)k0 >> 24) ^ tag)
                             | (((unsigned)k1 >> 24) ^ tag)
                             | (((unsigned)k2 >> 24) ^ tag)
                             | (((unsigned)k3 >> 24) ^ tag);
            if (m == 0) break;
        }
        // ---- tournament: u64 max == max value, ties -> smallest index ----
        const unsigned long long kA = k0 > k1 ? k0 : k1;
        const unsigned long long kB = k2 > k3 ? k2 : k3;
        const unsigned long long kw = kA > kB ? kA : kB;
        const int widx = (int)(0x00FFFFFFu - ((unsigned)kw & 0x00FFFFFFu));

        // centroid xyz: uniform-address LDS broadcast reads (parallel)
        const float sx = Xs[widx];
        const float sy = Ys[widx];
        const float sz = Zs[widx];
        if (tid == 0) {
            Samp[s * 3 + 0] = sx; Samp[s * 3 + 1] = sy; Samp[s * 3 + 2] = sz;
        }

        const v2f sxv = (v2f){sx, sx};
        const v2f syv = (v2f){sy, sy};
        const v2f szv = (v2f){sz, sz};

        v2f best2 = (v2f){-1.0f, -1.0f};
        int jx = 0, jy = 0;
        {
#pragma clang fp contract(off)
#pragma unroll
            for (int j = 0; j < 16; ++j) {
                // EXACT reference arithmetic per element:
                // ((dx*dx + dy*dy) + dz*dz), no FMA (contract off)
                const v2f dx = px[j] - sxv;
                const v2f dy = py[j] - syv;
                const v2f dz = pz[j] - szv;
                const v2f d  = (dx * dx + dy * dy) + dz * dz;
                const v2f m  = __builtin_elementwise_min(md[j], d);
                md[j] = m;
                // strict > keeps first occurrence within each half
                if (m.x > best2.x) jx = j;
                if (m.y > best2.y) jy = j;
                best2 = __builtin_elementwise_max(best2, m);
            }
        }
        // combine halves: every x-half index < every y-half index
        float    bestval;
        unsigned bestidx;
        if (best2.y > best2.x) { bestval = best2.y; bestidx = (unsigned)(tid * FPT + 16 + jy); }
        else                   { bestval = best2.x; bestidx = (unsigned)(tid * FPT + jx); }

        // wave max via DPP (VALU pipe), then first achieving lane via ballot
        const float wmax = wave_max_f32(bestval);
        const float smax = __int_as_float(
            __builtin_amdgcn_readlane(__float_as_int(wmax), 63));
        const unsigned long long msk = __ballot(bestval == smax);
        const int wl = __ffsll((long long)msk) - 1;          // lowest lane
        const unsigned widx_w =
            (unsigned)__builtin_amdgcn_readlane((int)bestidx, wl);

        // ---- delegate publishes tagged candidate for step s+1 ----
        if (lane == 0) {
            const unsigned ntag = (unsigned)(s + 1) & 0xFFu;
            *(volatile unsigned long long*)&slots[par ^ 1][wv] =
                ((unsigned long long)__float_as_uint(smax) << 32)
                | ((unsigned long long)ntag << 24)
                | (unsigned long long)(0x00FFFFFFu - widx_w);
        }
    }

    __syncthreads();   // order Samp writes before flush
    // coalesced flush of the sample buffer
    float* o = sample_xyz + (size_t)b * NS * 3;
    for (int i = tid; i < NS * 3; i += 256) o[i] = Samp[i];
}

// ---------------------------------------------------------------------------
// Kernel 2: ball query (first-64 in-radius indices, ascending) + feature
// gather. One 256-thread block per (b, s) centroid. Early-exit scan.
// d2 = na + nb - 2*dot; dot is an FMA CHAIN (XLA dot_general semantics),
// na/nb are non-FMA square-sums (XLA reduce semantics). VERIFIED rounds 2-10.
// ---------------------------------------------------------------------------
__global__ __launch_bounds__(256) void bq_gather_kernel(
    const float* __restrict__ xyz, const float* __restrict__ feat,
    const float* __restrict__ sample_xyz, float* __restrict__ out_feat)
{
    const int s   = blockIdx.x;
    const int b   = blockIdx.y;
    const int tid = threadIdx.x;

    __shared__ int   list[NK];
    __shared__ int   wavecnt[4];
    __shared__ float cen[3];

    if (tid < 3) cen[tid] = sample_xyz[((size_t)b * NS + s) * 3 + tid];
    __syncthreads();
    const float sx = cen[0], sy = cen[1], sz = cen[2];
    const float na = __fadd_rn(
        __fadd_rn(__fmul_rn(sx, sx), __fmul_rn(sy, sy)), __fmul_rn(sz, sz));
    const float* bxyz = xyz + (size_t)b * NPT * 3;

    int len = 0;
    for (int c0 = 0; c0 < NPT; c0 += 256) {
        const int idx = c0 + tid;
        const float x = bxyz[idx * 3 + 0];
        const float y = bxyz[idx * 3 + 1];
        const float z = bxyz[idx * 3 + 2];
        const float nb = __fadd_rn(
            __fadd_rn(__fmul_rn(x, x), __fmul_rn(y, y)), __fmul_rn(z, z));
        // dot as FMA chain (dot_general / matmul emitter semantics)
        const float dt = __fmaf_rn(sz, z, __fmaf_rn(sy, y, __fmul_rn(sx, x)));
        const float d2 = __fsub_rn(__fadd_rn(na, nb), __fmul_rn(2.0f, dt));
        const bool within = d2 < 0.04f;   // f32(0.2*0.2)

        const unsigned long long m = __ballot(within);
        const int wvq  = tid >> 6;
        const int lane = tid & 63;
        if (lane == 0) wavecnt[wvq] = __popcll(m);
        __syncthreads();
        const int w0 = wavecnt[0], w1 = wavecnt[1], w2 = wavecnt[2], w3 = wavecnt[3];
        int off = len;
        if (wvq > 0) off += w0;
        if (wvq > 1) off += w1;
        if (wvq > 2) off += w2;
        const int pre = __popcll(m & ((1ull << lane) - 1ull));
        const int pos = off + pre;
        if (within && pos < NK) list[pos] = idx;
        len += w0 + w1 + w2 + w3;
        __syncthreads();   // also orders list[] writes before gather reads
        if (len >= NK) break;
    }
    const int llen = len < NK ? len : NK;

    // gather: one wave per neighbor row (256 floats = 64 lanes x float4)
    const int lane = tid & 63;
    const int sub  = tid >> 6;   // 4 rows in flight per pass
    const float4* fbase = (const float4*)(feat + (size_t)b * NPT * NC);
    float4* obase = (float4*)(out_feat + (((size_t)b * NS + s) * (size_t)NK) * NC);
#pragma unroll
    for (int p = 0; p < NK / 4; ++p) {
        const int k   = p * 4 + sub;
        const int row = (k < llen) ? list[k] : NS;   // pad -> feat row 1024
        const float4 v = fbase[(size_t)row * (NC / 4) + lane];
        obase[(size_t)k * (NC / 4) + lane] = v;
    }
}

extern "C" void kernel_launch(void* const* d_in, const int* in_sizes, int n_in,
                              void* d_out, int out_size, void* d_ws, size_t ws_size,
                              hipStream_t stream) {
    const float* xyz  = (const float*)d_in[0];
    const float* feat = (const float*)d_in[1];
    float* out        = (float*)d_out;
    float* sample_xyz = out;                          // (B,S,3) = 12288 floats
    float* out_feat   = out + (size_t)NB * NS * 3;    // (B,S,K,C)

    fps_kernel<<<dim3(NB), dim3(256), 0, stream>>>(xyz, sample_xyz);
    bq_gather_kernel<<<dim3(NS, NB), dim3(256), 0, stream>>>(
        xyz, feat, sample_xyz, out_feat);
}

// Round 12
// 912.184 us; speedup vs baseline: 1.1621x; 1.1621x over previous
//
#include <hip/hip_runtime.h>
#include <cstdint>

#define NB   4      // batches
#define NPT  8192   // points
#define NC   256    // feature channels
#define NS   1024   // FPS samples
#define NK   64     // neighbors per ball
#define FPT  32     // points per thread in FPS (8192 / 256 threads)

typedef float v2f __attribute__((ext_vector_type(2)));

// ---------------------------------------------------------------------------
// DPP max step (f32, old=0 fill — safe: all reduced values >= 0).
// ---------------------------------------------------------------------------
template <int CTRL, int RMASK>
__device__ __forceinline__ float dpp_max_step(float x) {
    const int t = __builtin_amdgcn_update_dpp(
        0, __float_as_int(x), CTRL, RMASK, 0xf, false);
    return fmaxf(x, __int_as_float(t));
}
__device__ __forceinline__ float wave_max_f32(float x) {
    x = dpp_max_step<0x111, 0xf>(x);  // row_shr:1
    x = dpp_max_step<0x112, 0xf>(x);  // row_shr:2
    x = dpp_max_step<0x114, 0xf>(x);  // row_shr:4
    x = dpp_max_step<0x118, 0xf>(x);  // row_shr:8
    x = dpp_max_step<0x142, 0xa>(x);  // row_bcast:15 -> rows 1,3
    x = dpp_max_step<0x143, 0xc>(x);  // row_bcast:31 -> rows 2,3
    return x;                          // lane 63 holds wave max
}

// ---------------------------------------------------------------------------
// Kernel 1: farthest point sampling. One 256-thread block (4 waves = 1 per
// SIMD) per batch. Compute/reduce = round 7 VERBATIM (815 µs best; r8-r11
// alternatives all regressed). Change vs r7: payload-carrying per-wave slots
// remove the two dependent post-barrier LDS hops (key read -> extract ->
// Xs[widx] read) and the atomicMax.
//  - delegate wave publishes u64 key (f32bits(val)<<32 | 0xFFFFFFFF-idx —
//    IDENTICAL layout to r7, so max-tournament == r7's atomicMax winner,
//    ties -> smaller index) into keyb[wb][wv], plus the winner xyz into
//    THREE SCALAR b32 arrays pvx/pvy/pvz (b128 payloads caused r8's bank
//    conflicts; uniform b32/b64 broadcasts are conflict-free).
//  - winner xyz fetched PRE-barrier (uniform broadcast Xs[widx_w] by the
//    whole wave, concurrent across waves) — off the serial path.
//  - post-barrier: 4 uniform b64 + 12 uniform b32 reads (parallel, one
//    lgkm wait) + 3-compare u64 tournament + cndmask xyz select.
//  - parity double-buffer, one barrier per step; slots of parity p are
//    read at step-top(s: s&1==p) and rewritten at step-bottom(s+1), which
//    is after barrier(s) -> race-free. Step-0 slots prefilled (+inf key,
//    point-0 xyz) => deterministic start at index 0.
// First-occurrence argmax (VERIFIED r1-r11): x-half = tid*32+0..15, y-half
// = tid*32+16..31; strict-> per half keeps earliest index; combine prefers
// x; lowest achieving lane via ballot+ffs; cross-wave via key compare.
// NOTE: non-FMA left-to-right distance arithmetic (contract off) is VERIFIED
// bit-exact vs the reference (rounds 1-11). Do not "optimize" into FMA.
// ---------------------------------------------------------------------------
__global__ __launch_bounds__(256, 1) void fps_kernel(
    const float* __restrict__ xyz, float* __restrict__ sample_xyz)
{
    const int b    = blockIdx.x;
    const int tid  = threadIdx.x;
    const int lane = tid & 63;
    const int wv   = tid >> 6;

    __shared__ float Xs[NPT], Ys[NPT], Zs[NPT];        // 96 KB SoA copy
    __shared__ float Samp[NS * 3];                     // 12 KB result buffer
    __shared__ unsigned long long keyb[2][4];          // per-wave keys
    __shared__ float pvx[2][4], pvy[2][4], pvz[2][4];  // per-wave winner xyz

    const float* base = xyz + (size_t)b * NPT * 3;

    v2f px[16], py[16], pz[16], md[16];
#pragma unroll
    for (int j = 0; j < 16; ++j) {
        const int pa = tid * FPT + j;         // x-half point
        const int pb = tid * FPT + 16 + j;    // y-half point
        const float ax = base[pa * 3 + 0], ay = base[pa * 3 + 1], az = base[pa * 3 + 2];
        const float bx = base[pb * 3 + 0], by = base[pb * 3 + 1], bz = base[pb * 3 + 2];
        px[j] = (v2f){ax, bx};
        py[j] = (v2f){ay, by};
        pz[j] = (v2f){az, bz};
        md[j] = (v2f){__builtin_inff(), __builtin_inff()};
        Xs[pa] = ax; Ys[pa] = ay; Zs[pa] = az;
        Xs[pb] = bx; Ys[pb] = by; Zs[pb] = bz;
        if (tid == 0 && j == 0) {
            // step-0 prefill: +inf key, idx 0, its xyz -> point 0 wins step 0
            keyb[0][0] = ((unsigned long long)0x7F800000u << 32) | 0xFFFFFFFFull;
            pvx[0][0] = ax; pvy[0][0] = ay; pvz[0][0] = az;
        }
    }
    if (tid >= 1 && tid < 4) {
        keyb[0][tid] = 0ull;                  // never wins vs +inf
        pvx[0][tid] = 0.0f; pvy[0][tid] = 0.0f; pvz[0][tid] = 0.0f;
    }
    __syncthreads();

    for (int s = 0; s < NS; ++s) {
        const int rb = s & 1;        // read-buffer parity
        const int wb = rb ^ 1;       // write-buffer parity

        // ---- winner pick: parallel uniform b64/b32 reads + tournament ----
        const unsigned long long k0 = keyb[rb][0];
        const unsigned long long k1 = keyb[rb][1];
        const unsigned long long k2 = keyb[rb][2];
        const unsigned long long k3 = keyb[rb][3];
        const float x0 = pvx[rb][0], y0 = pvy[rb][0], z0 = pvz[rb][0];
        const float x1 = pvx[rb][1], y1 = pvy[rb][1], z1 = pvz[rb][1];
        const float x2 = pvx[rb][2], y2 = pvy[rb][2], z2 = pvz[rb][2];
        const float x3 = pvx[rb][3], y3 = pvy[rb][3], z3 = pvz[rb][3];
        // full-key compares: max value, ties -> larger ~idx = smaller idx
        const bool sA = k1 > k0;
        const unsigned long long kA = sA ? k1 : k0;
        const float xA = sA ? x1 : x0, yA = sA ? y1 : y0, zA = sA ? z1 : z0;
        const bool sB = k3 > k2;
        const unsigned long long kB = sB ? k3 : k2;
        const float xB = sB ? x3 : x2, yB = sB ? y3 : y2, zB = sB ? z3 : z2;
        const bool sC = kB > kA;
        const float sx = sC ? xB : xA;
        const float sy = sC ? yB : yA;
        const float sz = sC ? zB : zA;

        if (tid == 0) {
            Samp[s * 3 + 0] = sx; Samp[s * 3 + 1] = sy; Samp[s * 3 + 2] = sz;
        }

        const v2f sxv = (v2f){sx, sx};
        const v2f syv = (v2f){sy, sy};
        const v2f szv = (v2f){sz, sz};

        v2f best2 = (v2f){-1.0f, -1.0f};
        int jx = 0, jy = 0;
        {
#pragma clang fp contract(off)
#pragma unroll
            for (int j = 0; j < 16; ++j) {
                // EXACT reference arithmetic per element:
                // ((dx*dx + dy*dy) + dz*dz), no FMA (contract off)
                const v2f dx = px[j] - sxv;
                const v2f dy = py[j] - syv;
                const v2f dz = pz[j] - szv;
                const v2f d  = (dx * dx + dy * dy) + dz * dz;
                const v2f m  = __builtin_elementwise_min(md[j], d);
                md[j] = m;
                // strict > keeps first occurrence within each half
                if (m.x > best2.x) jx = j;
                if (m.y > best2.y) jy = j;
                best2 = __builtin_elementwise_max(best2, m);
            }
        }
        // combine halves: every x-half index < every y-half index
        float    bestval;
        unsigned bestidx;
        if (best2.y > best2.x) { bestval = best2.y; bestidx = (unsigned)(tid * FPT + 16 + jy); }
        else                   { bestval = best2.x; bestidx = (unsigned)(tid * FPT + jx); }

        // wave max via DPP (VALU pipe), then first achieving lane via ballot
        const float wmax = wave_max_f32(bestval);
        const float smax = __int_as_float(
            __builtin_amdgcn_readlane(__float_as_int(wmax), 63));
        const unsigned long long msk = __ballot(bestval == smax);
        const int wl = __ffsll((long long)msk) - 1;          // lowest lane
        const unsigned widx_w =
            (unsigned)__builtin_amdgcn_readlane((int)bestidx, wl);

        // pre-barrier winner-xyz fetch: uniform broadcast reads, concurrent
        // across the 4 waves (off the post-barrier critical path)
        const float wx = Xs[widx_w];
        const float wy = Ys[widx_w];
        const float wz = Zs[widx_w];
        if (lane == 0) {
            keyb[wb][wv] =
                ((unsigned long long)__float_as_uint(smax) << 32)
                | (unsigned long long)(0xFFFFFFFFu - widx_w);
            pvx[wb][wv] = wx; pvy[wb][wv] = wy; pvz[wb][wv] = wz;
        }
        __syncthreads();
    }

    // coalesced flush of the sample buffer
    float* o = sample_xyz + (size_t)b * NS * 3;
    for (int i = tid; i < NS * 3; i += 256) o[i] = Samp[i];
}

// ---------------------------------------------------------------------------
// Kernel 2: ball query (first-64 in-radius indices, ascending) + feature
// gather. One 256-thread block per (b, s) centroid. Early-exit scan.
// d2 = na + nb - 2*dot; dot is an FMA CHAIN (XLA dot_general semantics),
// na/nb are non-FMA square-sums (XLA reduce semantics). VERIFIED rounds 2-11.
// ---------------------------------------------------------------------------
__global__ __launch_bounds__(256) void bq_gather_kernel(
    const float* __restrict__ xyz, const float* __restrict__ feat,
    const float* __restrict__ sample_xyz, float* __restrict__ out_feat)
{
    const int s   = blockIdx.x;
    const int b   = blockIdx.y;
    const int tid = threadIdx.x;

    __shared__ int   list[NK];
    __shared__ int   wavecnt[4];
    __shared__ float cen[3];

    if (tid < 3) cen[tid] = sample_xyz[((size_t)b * NS + s) * 3 + tid];
    __syncthreads();
    const float sx = cen[0], sy = cen[1], sz = cen[2];
    const float na = __fadd_rn(
        __fadd_rn(__fmul_rn(sx, sx), __fmul_rn(sy, sy)), __fmul_rn(sz, sz));
    const float* bxyz = xyz + (size_t)b * NPT * 3;

    int len = 0;
    for (int c0 = 0; c0 < NPT; c0 += 256) {
        const int idx = c0 + tid;
        const float x = bxyz[idx * 3 + 0];
        const float y = bxyz[idx * 3 + 1];
        const float z = bxyz[idx * 3 + 2];
        const float nb = __fadd_rn(
            __fadd_rn(__fmul_rn(x, x), __fmul_rn(y, y)), __fmul_rn(z, z));
        // dot as FMA chain (dot_general / matmul emitter semantics)
        const float dt = __fmaf_rn(sz, z, __fmaf_rn(sy, y, __fmul_rn(sx, x)));
        const float d2 = __fsub_rn(__fadd_rn(na, nb), __fmul_rn(2.0f, dt));
        const bool within = d2 < 0.04f;   // f32(0.2*0.2)

        const unsigned long long m = __ballot(within);
        const int wvq  = tid >> 6;
        const int lane = tid & 63;
        if (lane == 0) wavecnt[wvq] = __popcll(m);
        __syncthreads();
        const int w0 = wavecnt[0], w1 = wavecnt[1], w2 = wavecnt[2], w3 = wavecnt[3];
        int off = len;
        if (wvq > 0) off += w0;
        if (wvq > 1) off += w1;
        if (wvq > 2) off += w2;
        const int pre = __popcll(m & ((1ull << lane) - 1ull));
        const int pos = off + pre;
        if (within && pos < NK) list[pos] = idx;
        len += w0 + w1 + w2 + w3;
        __syncthreads();   // also orders list[] writes before gather reads
        if (len >= NK) break;
    }
    const int llen = len < NK ? len : NK;

    // gather: one wave per neighbor row (256 floats = 64 lanes x float4)
    const int lane = tid & 63;
    const int sub  = tid >> 6;   // 4 rows in flight per pass
    const float4* fbase = (const float4*)(feat + (size_t)b * NPT * NC);
    float4* obase = (float4*)(out_feat + (((size_t)b * NS + s) * (size_t)NK) * NC);
#pragma unroll
    for (int p = 0; p < NK / 4; ++p) {
        const int k   = p * 4 + sub;
        const int row = (k < llen) ? list[k] : NS;   // pad -> feat row 1024
        const float4 v = fbase[(size_t)row * (NC / 4) + lane];
        obase[(size_t)k * (NC / 4) + lane] = v;
    }
}

extern "C" void kernel_launch(void* const* d_in, const int* in_sizes, int n_in,
                              void* d_out, int out_size, void* d_ws, size_t ws_size,
                              hipStream_t stream) {
    const float* xyz  = (const float*)d_in[0];
    const float* feat = (const float*)d_in[1];
    float* out        = (float*)d_out;
    float* sample_xyz = out;                          // (B,S,3) = 12288 floats
    float* out_feat   = out + (size_t)NB * NS * 3;    // (B,S,K,C)

    fps_kernel<<<dim3(NB), dim3(256), 0, stream>>>(xyz, sample_xyz);
    bq_gather_kernel<<<dim3(NS, NB), dim3(256), 0, stream>>>(
        xyz, feat, sample_xyz, out_feat);
}